// Round 15
// baseline (14.735 us; speedup 1.0000x reference)
//
#include <hip/hip_runtime.h>
#include <math.h>

#define BLOCK 256
#define TPT 2   // tokens per thread

typedef float v2f __attribute__((ext_vector_type(2)));
typedef float v4f __attribute__((ext_vector_type(4)));

// Even/odd-parity partial sums monoid for type-2 roots, packed as v2f (E,O).
// Split-complex product: r = (aE*bE + aO*bO, aO*bE + aE*bO) — commutative.
// With packed-f32 (v_pk_mul/v_pk_fma + op_sel broadcasts/swaps) this is 2
// instructions instead of 4 scalar. Every intermediate is a sum of POSITIVE
// partial weight-products (bounded by the softmax denominator — numerically
// safe; the Π(g±h) shortcut is NOT, see R8's absmax=1.02 failure).
__device__ __forceinline__ v2f mergeEO(v2f a, v2f b) {
    v2f bE = __builtin_shufflevector(b, b, 0, 0);
    v2f bO = __builtin_shufflevector(b, b, 1, 1);
    v2f as = __builtin_shufflevector(a, a, 1, 0);
    return __builtin_elementwise_fma(a, bE, as * bO);
}

// weights = softmax(20 * x.r) over 240 unit-norm E8 roots, closed form (O(8)):
//  Type-1 (112): rank-1 factorization A=u+v, B=u-v, u=s*g^2, v=s*h^2
//  Type-2 (128): even-parity monoid over (g,h)
//  g/h = exp2(+-K2*x_j - C/8), s = exp2(-C/4), C = (20/ln2)*|x| (all exps <= 0).
// Pair-packed throughout: (g,h), (E,O), (prefixA, suffixA-reversed) all live
// in v2f so the backend can emit v_pk_* (2 f32/instr). Materialized arrays
// (R6/R12 ILP structure) retained — fused running-prefix was ~1us slower.
__device__ __forceinline__ void e8q_token(const float xs[8], float o[8]) {
    v2f n2p = {0.0f, 0.0f};
#pragma unroll
    for (int j = 0; j < 4; ++j) {
        v2f xp = {xs[2 * j], xs[2 * j + 1]};
        n2p = __builtin_elementwise_fma(xp, xp, n2p);
    }
    const float xn = __builtin_amdgcn_sqrtf(n2p.x + n2p.y);

    const float K2 = 10.201358186637847f;       // (20/ln2)/(2*sqrt(2))
    const float C  = 28.853900817779268f * xn;  // (20/ln2)*|x|
    const float Ce = 0.125f * C;
    const float s  = __builtin_amdgcn_exp2f(-0.25f * C);

    const v2f KK = {K2, -K2};
    const v2f CC = {-Ce, -Ce};
    const v2f ss = {s, s};

    v2f gh[8];
    float A[8], B[8];
#pragma unroll
    for (int j = 0; j < 8; ++j) {
        v2f xx = {xs[j], xs[j]};
        v2f arg = __builtin_elementwise_fma(xx, KK, CC);   // (K2 x - Ce, -K2 x - Ce)
        gh[j] = (v2f){__builtin_amdgcn_exp2f(arg.x), __builtin_amdgcn_exp2f(arg.y)};
        v2f ab  = gh[j] * gh[j];       // (g^2, h^2)
        v2f sab = ss * ab;             // (u, v)
        A[j] = sab.x + sab.y;          // u + v
        B[j] = sab.x - sab.y;          // u - v
    }

    // Type-1: packed (prefix, reversed-suffix) chain: ps[k] = (preA[k], sufA[7-k]).
    v2f ps[8];
    ps[0] = (v2f){A[0], A[7]};
#pragma unroll
    for (int k = 1; k < 8; ++k) ps[k] = ps[k - 1] + (v2f){A[k], A[7 - k]};

    // EA[j] = preA[j-1] + sufA[j+1] (exclude-one sums; pure adds, no cancellation)
    float EA[8];
    EA[0] = ps[6].y;   // sufA[1]
    EA[7] = ps[6].x;   // preA[6]
#pragma unroll
    for (int j = 1; j <= 3; ++j) {
        v2f e = ps[j - 1] + __builtin_shufflevector(ps[6 - j], ps[6 - j], 1, 0);
        EA[j] = e.x;        // preA[j-1] + sufA[j+1]
        EA[7 - j] = e.y;    // preA[6-j] + sufA[8-j]
    }

    // s1 = sum_{j<7} A[j]*sufA[j+1]  (all 112 type-1 weights; positive adds)
    v2f s1p = {0.0f, 0.0f};
    s1p = __builtin_elementwise_fma((v2f){A[0], A[1]}, (v2f){ps[6].y, ps[5].y}, s1p);
    s1p = __builtin_elementwise_fma((v2f){A[2], A[3]}, (v2f){ps[4].y, ps[3].y}, s1p);
    s1p = __builtin_elementwise_fma((v2f){A[4], A[5]}, (v2f){ps[2].y, ps[1].y}, s1p);
    const float s1 = fmaf(A[6], ps[0].y, s1p.x + s1p.y);

    // Type-2: parity monoid prefix/suffix (two parallel chains, independent merges)
    v2f pre[8], suf[8];
    pre[0] = gh[0];
#pragma unroll
    for (int j = 1; j < 8; ++j) pre[j] = mergeEO(pre[j - 1], gh[j]);
    suf[7] = gh[7];
#pragma unroll
    for (int j = 6; j >= 1; --j) suf[j] = mergeEO(gh[j], suf[j + 1]);

    const float s2 = pre[7].x;

    v2f ex[8];
    ex[0] = suf[1];
    ex[7] = pre[6];
#pragma unroll
    for (int j = 1; j < 7; ++j) ex[j] = mergeEO(pre[j - 1], suf[j + 1]);

    const float inv = __builtin_amdgcn_rcpf(s1 + s2);
    const float c1 = 0.70710678118654752f * inv;   // 1/sqrt2
    const float c2 = 0.35355339059327376f * inv;   // 1/(2*sqrt2)

#pragma unroll
    for (int j = 0; j < 8; ++j) {
        v2f m = gh[j] * ex[j];         // (g*exE, h*exO)
        float t2 = m.x - m.y;
        float t1 = B[j] * EA[j];
        o[j] = fmaf(c1, t1, c2 * t2);
    }
}

// R14 structure (best, 13.66us): strided up-front loads, wave-local
// parity-split LDS staging, per-pass interleaved dense nontemporal flush
// (nt CONFIRMED by R13 A/B: cached stores cost +1.9us), no __syncthreads.
__global__ __launch_bounds__(BLOCK, 4) void e8q_kernel(const float* __restrict__ x,
                                                       float* __restrict__ out) {
    __shared__ v4f outA[4][64 * TPT];
    __shared__ v4f outB[4][64 * TPT];

    const int tid = threadIdx.x;
    const int w = tid >> 6;      // wave id
    const int l = tid & 63;      // lane id
    const size_t T0 = (size_t)blockIdx.x * (BLOCK * TPT);
    v4f* ov = (v4f*)out + T0 * 2;

    // Issue all loads up front (4x dwordx4) for MLP.
    v4f xv[TPT][2];
#pragma unroll
    for (int p = 0; p < TPT; ++p) {
        const v4f* xp = (const v4f*)(x + (T0 + tid + (size_t)p * BLOCK) * 8);
        xv[p][0] = xp[0];
        xv[p][1] = xp[1];
    }

#pragma unroll
    for (int p = 0; p < TPT; ++p) {
        float xs[8] = {xv[p][0].x, xv[p][0].y, xv[p][0].z, xv[p][0].w,
                       xv[p][1].x, xv[p][1].y, xv[p][1].z, xv[p][1].w};
        float o[8];
        e8q_token(xs, o);

        const int tl = p * 64 + l;
        outA[w][tl] = (v4f){o[0], o[1], o[2], o[3]};
        outB[w][tl] = (v4f){o[4], o[5], o[6], o[7]};

        // Flush pass p immediately (wave-local slots [128p,128p+128)).
#pragma unroll
        for (int jj = 0; jj < 2; ++jj) {
            const int j = 2 * p + jj;
            const int sidx = j * 64 + l;
            v4f val = (sidx & 1) ? outB[w][sidx >> 1] : outA[w][sidx >> 1];
            const int gslot = (j < 2) ? (128 * w + j * 64 + l)
                                      : (512 + 128 * w + (j - 2) * 64 + l);
            __builtin_nontemporal_store(val, ov + gslot);
        }
    }
}

extern "C" void kernel_launch(void* const* d_in, const int* in_sizes, int n_in,
                              void* d_out, int out_size, void* d_ws, size_t ws_size,
                              hipStream_t stream) {
    const float* x = (const float*)d_in[0];
    float* out = (float*)d_out;

    const int tokens = in_sizes[0] / 8;        // 1,048,576
    const int grid = tokens / (BLOCK * TPT);   // 2048

    e8q_kernel<<<grid, BLOCK, 0, stream>>>(x, out);
}

// Round 16
// 14.584 us; speedup vs baseline: 1.0103x; 1.0103x over previous
//
#include <hip/hip_runtime.h>
#include <math.h>

#define BLOCK 256
#define TPT 2   // tokens per thread per chunk

typedef float v4f __attribute__((ext_vector_type(4)));

// Even/odd-parity partial sums monoid for type-2 roots. E and O are sums of
// POSITIVE partial weight-products of actual parity classes — every
// intermediate is bounded by the softmax denominator (numerically safe).
// (The Π(g±h) product shortcut is NOT safe — R8's absmax=1.02 failure.)
struct EO { float E, O; };
__device__ __forceinline__ EO mergeEO(EO a, EO b) {
    EO r;
    r.E = fmaf(a.E, b.E, a.O * b.O);
    r.O = fmaf(a.E, b.O, a.O * b.E);
    return r;
}

// weights = softmax(20 * x.r) over 240 unit-norm E8 roots, closed form (O(8)):
//  Type-1 (112): rank-1 factorization A=u+v, B=u-v, u=s*g^2, v=s*h^2
//  Type-2 (128): even-parity monoid over (g,h)
//  g/h = exp2(+-K2*x_j - C/8), s = exp2(-C/4), C = (20/ln2)*|x| (all exps <= 0).
// Scalar materialized-array version (R6/R12/R14): pre/suf chains run in
// parallel, 6 independent ex-merges — best measured ILP. (v2f packing (R15)
// and fused running-prefix (R9/R11) both regressed ~1us.)
__device__ __forceinline__ void e8q_token(const float xs[8], float o[8]) {
    float n2 = 0.0f;
#pragma unroll
    for (int j = 0; j < 8; ++j) n2 = fmaf(xs[j], xs[j], n2);
    const float xn = __builtin_amdgcn_sqrtf(n2);

    const float K2 = 10.201358186637847f;       // (20/ln2)/(2*sqrt(2))
    const float C  = 28.853900817779268f * xn;  // (20/ln2)*|x|
    const float Ce = 0.125f * C;
    const float s  = __builtin_amdgcn_exp2f(-0.25f * C);

    float A[8], B[8], g[8], h[8];
#pragma unroll
    for (int j = 0; j < 8; ++j) {
        g[j] = __builtin_amdgcn_exp2f(fmaf(K2, xs[j], -Ce));
        h[j] = __builtin_amdgcn_exp2f(fmaf(-K2, xs[j], -Ce));
        float a = g[j] * g[j];
        float b = h[j] * h[j];
        float sa = s * a;                // u_j
        A[j] = fmaf(s, b, sa);           // u + v
        B[j] = fmaf(-s, b, sa);          // u - v
    }

    // Type-1: exclude-one sums via prefix+suffix adds (no cancelling subtraction)
    float preA[8], sufA[8];
    preA[0] = A[0];
#pragma unroll
    for (int j = 1; j < 8; ++j) preA[j] = preA[j - 1] + A[j];
    sufA[7] = A[7];
#pragma unroll
    for (int j = 6; j >= 0; --j) sufA[j] = sufA[j + 1] + A[j];

    float EA[8];
    EA[0] = sufA[1];
    EA[7] = preA[6];
#pragma unroll
    for (int j = 1; j < 7; ++j) EA[j] = preA[j - 1] + sufA[j + 1];

    float s1 = 0.0f;   // sum_{i<j} A_i A_j (all 112 type-1 weights)
#pragma unroll
    for (int j = 0; j < 7; ++j) s1 = fmaf(A[j], sufA[j + 1], s1);

    // Type-2: parity monoid prefix/suffix (two parallel chains, independent merges)
    EO pre[8], suf[8];
    pre[0] = {g[0], h[0]};
#pragma unroll
    for (int j = 1; j < 8; ++j) pre[j] = mergeEO(pre[j - 1], {g[j], h[j]});
    suf[7] = {g[7], h[7]};
#pragma unroll
    for (int j = 6; j >= 1; --j) suf[j] = mergeEO({g[j], h[j]}, suf[j + 1]);

    const float s2 = pre[7].E;

    EO ex[8];
    ex[0] = suf[1];
    ex[7] = pre[6];
#pragma unroll
    for (int j = 1; j < 7; ++j) ex[j] = mergeEO(pre[j - 1], suf[j + 1]);

    const float inv = __builtin_amdgcn_rcpf(s1 + s2);
    const float c1 = 0.70710678118654752f * inv;   // 1/sqrt2
    const float c2 = 0.35355339059327376f * inv;   // 1/(2*sqrt2)

#pragma unroll
    for (int j = 0; j < 8; ++j) {
        float t1 = B[j] * EA[j];
        float t2 = fmaf(g[j], ex[j].E, -(h[j] * ex[j].O));
        o[j] = fmaf(c1, t1, c2 * t2);
    }
}

// R14's per-chunk body: compute TPT tokens, stage to wave-local parity-split
// LDS, flush densely (nt) per pass. No __syncthreads anywhere.
__device__ __forceinline__ void process_chunk(const v4f xv[TPT][2], float* out,
                                              size_t T0, int w, int l,
                                              v4f (*outA)[64 * TPT],
                                              v4f (*outB)[64 * TPT]) {
    v4f* ov = (v4f*)out + T0 * 2;
#pragma unroll
    for (int p = 0; p < TPT; ++p) {
        float xs[8] = {xv[p][0].x, xv[p][0].y, xv[p][0].z, xv[p][0].w,
                       xv[p][1].x, xv[p][1].y, xv[p][1].z, xv[p][1].w};
        float o[8];
        e8q_token(xs, o);

        const int tl = p * 64 + l;
        outA[w][tl] = (v4f){o[0], o[1], o[2], o[3]};
        outB[w][tl] = (v4f){o[4], o[5], o[6], o[7]};

        // Flush pass p immediately (wave-local slots [128p,128p+128)).
#pragma unroll
        for (int jj = 0; jj < 2; ++jj) {
            const int j = 2 * p + jj;
            const int sidx = j * 64 + l;
            v4f val = (sidx & 1) ? outB[w][sidx >> 1] : outA[w][sidx >> 1];
            const int gslot = (j < 2) ? (128 * w + j * 64 + l)
                                      : (512 + 128 * w + (j - 2) * 64 + l);
            __builtin_nontemporal_store(val, ov + gslot);
        }
    }
}

// Cross-chunk software pipeline: each block handles TWO 512-token chunks
// straight-line. ALL 8 loads issue up front — chunk-B's 4 stay outstanding
// (vmcnt(4)) under chunk-A's ~2300-cycle compute+flush, hiding B's HBM
// latency+BW; A's nt-store drain overlaps B's compute symmetrically.
__global__ __launch_bounds__(BLOCK, 4) void e8q_kernel(const float* __restrict__ x,
                                                       float* __restrict__ out) {
    __shared__ v4f outA[4][64 * TPT];
    __shared__ v4f outB[4][64 * TPT];

    const int tid = threadIdx.x;
    const int w = tid >> 6;      // wave id
    const int l = tid & 63;      // lane id

    const size_t CH = (size_t)BLOCK * TPT;              // 512 tokens per chunk
    const size_t T0a = (size_t)blockIdx.x * CH;
    const size_t T0b = T0a + (size_t)gridDim.x * CH;

    v4f bufA[TPT][2], bufB[TPT][2];
#pragma unroll
    for (int p = 0; p < TPT; ++p) {
        const v4f* xp = (const v4f*)(x + (T0a + tid + (size_t)p * BLOCK) * 8);
        bufA[p][0] = xp[0];
        bufA[p][1] = xp[1];
    }
#pragma unroll
    for (int p = 0; p < TPT; ++p) {
        const v4f* xp = (const v4f*)(x + (T0b + tid + (size_t)p * BLOCK) * 8);
        bufB[p][0] = xp[0];
        bufB[p][1] = xp[1];
    }

    process_chunk(bufA, out, T0a, w, l, outA, outB);
    // LDS regions reused: same-wave ds ordering guarantees chunk-A's flush
    // reads complete before chunk-B's staging writes land.
    process_chunk(bufB, out, T0b, w, l, outA, outB);
}

extern "C" void kernel_launch(void* const* d_in, const int* in_sizes, int n_in,
                              void* d_out, int out_size, void* d_ws, size_t ws_size,
                              hipStream_t stream) {
    const float* x = (const float*)d_in[0];
    float* out = (float*)d_out;

    const int tokens = in_sizes[0] / 8;            // 1,048,576
    const int grid = tokens / (BLOCK * TPT * 2);   // 1024 (two chunks per block)

    e8q_kernel<<<grid, BLOCK, 0, stream>>>(x, out);
}

// Round 17
// 13.660 us; speedup vs baseline: 1.0787x; 1.0677x over previous
//
#include <hip/hip_runtime.h>
#include <math.h>

#define BLOCK 256
#define TPT 2   // tokens per thread

typedef float v4f __attribute__((ext_vector_type(4)));

// Even/odd-parity partial sums monoid for type-2 roots. E and O are sums of
// POSITIVE partial weight-products of actual parity classes — every
// intermediate is bounded by the softmax denominator (numerically safe).
// (The Π(g±h) product shortcut is NOT safe — R8's absmax=1.02 failure.)
struct EO { float E, O; };
__device__ __forceinline__ EO mergeEO(EO a, EO b) {
    EO r;
    r.E = fmaf(a.E, b.E, a.O * b.O);
    r.O = fmaf(a.E, b.O, a.O * b.E);
    return r;
}

// weights = softmax(20 * x.r) over 240 unit-norm E8 roots, closed form (O(8)):
//  Type-1 (112): rank-1 factorization A=u+v, B=u-v, u=s*g^2, v=s*h^2
//  Type-2 (128): even-parity monoid over (g,h)
//  g/h = exp2(+-K2*x_j - C/8), s = exp2(-C/4), C = (20/ln2)*|x| (all exps <= 0).
// Materialized pre[]/suf[]/ex[] arrays on purpose: the pre- and suf-chains run
// in parallel and the 6 ex-merges are independent — best measured ILP
// (fused running-prefix R9/R11 and v2f packing R15 both ~1us slower).
__device__ __forceinline__ void e8q_token(const float xs[8], float o[8]) {
    float n2 = 0.0f;
#pragma unroll
    for (int j = 0; j < 8; ++j) n2 = fmaf(xs[j], xs[j], n2);
    const float xn = __builtin_amdgcn_sqrtf(n2);

    const float K2 = 10.201358186637847f;       // (20/ln2)/(2*sqrt(2))
    const float C  = 28.853900817779268f * xn;  // (20/ln2)*|x|
    const float Ce = 0.125f * C;
    const float s  = __builtin_amdgcn_exp2f(-0.25f * C);

    float A[8], B[8], g[8], h[8];
#pragma unroll
    for (int j = 0; j < 8; ++j) {
        g[j] = __builtin_amdgcn_exp2f(fmaf(K2, xs[j], -Ce));
        h[j] = __builtin_amdgcn_exp2f(fmaf(-K2, xs[j], -Ce));
        float a = g[j] * g[j];
        float b = h[j] * h[j];
        float sa = s * a;                // u_j
        A[j] = fmaf(s, b, sa);           // u + v
        B[j] = fmaf(-s, b, sa);          // u - v
    }

    // Type-1: exclude-one sums via prefix+suffix adds (no cancelling subtraction)
    float preA[8], sufA[8];
    preA[0] = A[0];
#pragma unroll
    for (int j = 1; j < 8; ++j) preA[j] = preA[j - 1] + A[j];
    sufA[7] = A[7];
#pragma unroll
    for (int j = 6; j >= 0; --j) sufA[j] = sufA[j + 1] + A[j];

    float EA[8];
    EA[0] = sufA[1];
    EA[7] = preA[6];
#pragma unroll
    for (int j = 1; j < 7; ++j) EA[j] = preA[j - 1] + sufA[j + 1];

    float s1 = 0.0f;   // sum_{i<j} A_i A_j (all 112 type-1 weights)
#pragma unroll
    for (int j = 0; j < 7; ++j) s1 = fmaf(A[j], sufA[j + 1], s1);

    // Type-2: parity monoid prefix/suffix (two parallel chains, independent merges)
    EO pre[8], suf[8];
    pre[0] = {g[0], h[0]};
#pragma unroll
    for (int j = 1; j < 8; ++j) pre[j] = mergeEO(pre[j - 1], {g[j], h[j]});
    suf[7] = {g[7], h[7]};
#pragma unroll
    for (int j = 6; j >= 1; --j) suf[j] = mergeEO({g[j], h[j]}, suf[j + 1]);

    const float s2 = pre[7].E;

    EO ex[8];
    ex[0] = suf[1];
    ex[7] = pre[6];
#pragma unroll
    for (int j = 1; j < 7; ++j) ex[j] = mergeEO(pre[j - 1], suf[j + 1]);

    const float inv = __builtin_amdgcn_rcpf(s1 + s2);
    const float c1 = 0.70710678118654752f * inv;   // 1/sqrt2
    const float c2 = 0.35355339059327376f * inv;   // 1/(2*sqrt2)

#pragma unroll
    for (int j = 0; j < 8; ++j) {
        float t1 = B[j] * EA[j];
        float t2 = fmaf(g[j], ex[j].E, -(h[j] * ex[j].O));
        o[j] = fmaf(c1, t1, c2 * t2);
    }
}

// Best-known structure (R14, 13.66us): strided up-front loads (4x dwordx4 for
// MLP), wave-local parity-split LDS staging, per-pass interleaved dense
// nontemporal flush (nt CONFIRMED by R13 A/B: cached stores +1.9us), no
// __syncthreads (waves only read LDS they wrote; same-wave ds ordering via
// compiler lgkmcnt).
__global__ __launch_bounds__(BLOCK, 4) void e8q_kernel(const float* __restrict__ x,
                                                       float* __restrict__ out) {
    __shared__ v4f outA[4][64 * TPT];
    __shared__ v4f outB[4][64 * TPT];

    const int tid = threadIdx.x;
    const int w = tid >> 6;      // wave id
    const int l = tid & 63;      // lane id
    const size_t T0 = (size_t)blockIdx.x * (BLOCK * TPT);
    v4f* ov = (v4f*)out + T0 * 2;

    // Issue all loads up front (4x dwordx4) for MLP.
    v4f xv[TPT][2];
#pragma unroll
    for (int p = 0; p < TPT; ++p) {
        const v4f* xp = (const v4f*)(x + (T0 + tid + (size_t)p * BLOCK) * 8);
        xv[p][0] = xp[0];
        xv[p][1] = xp[1];
    }

#pragma unroll
    for (int p = 0; p < TPT; ++p) {
        // Compute pass p (block-token p*256 + 64w + l).
        float xs[8] = {xv[p][0].x, xv[p][0].y, xv[p][0].z, xv[p][0].w,
                       xv[p][1].x, xv[p][1].y, xv[p][1].z, xv[p][1].w};
        float o[8];
        e8q_token(xs, o);

        // Stage to wave-local parity-split LDS.
        const int tl = p * 64 + l;
        outA[w][tl] = (v4f){o[0], o[1], o[2], o[3]};
        outB[w][tl] = (v4f){o[4], o[5], o[6], o[7]};

        // Flush pass p immediately: wave-local slots [128p, 128p+128) =
        // flush iterations j in {2p, 2p+1}. Dense 1KB per store instruction.
#pragma unroll
        for (int jj = 0; jj < 2; ++jj) {
            const int j = 2 * p + jj;
            const int s = j * 64 + l;
            v4f val = (s & 1) ? outB[w][s >> 1] : outA[w][s >> 1];
            const int gslot = (j < 2) ? (128 * w + j * 64 + l)
                                      : (512 + 128 * w + (j - 2) * 64 + l);
            __builtin_nontemporal_store(val, ov + gslot);
        }
    }
}

extern "C" void kernel_launch(void* const* d_in, const int* in_sizes, int n_in,
                              void* d_out, int out_size, void* d_ws, size_t ws_size,
                              hipStream_t stream) {
    const float* x = (const float*)d_in[0];
    float* out = (float*)d_out;

    const int tokens = in_sizes[0] / 8;        // 1,048,576
    const int grid = tokens / (BLOCK * TPT);   // 2048

    e8q_kernel<<<grid, BLOCK, 0, stream>>>(x, out);
}